// Round 2
// baseline (563.508 us; speedup 1.0000x reference)
//
#include <hip/hip_runtime.h>
#include <hip/hip_bf16.h>

#define B_ 4
#define C_ 256
#define H_ 256
#define W_ 256
#define N_ 1024   // 32*32 tokens
#define KC 32     // key channels

typedef __attribute__((ext_vector_type(8))) short short8;   // 8 bf16 (4 VGPRs)
typedef __attribute__((ext_vector_type(4))) float floatx4;  // MFMA C/D

__device__ __forceinline__ short f2bf(float x) {
    __hip_bfloat16 h = __float2bfloat16(x);
    return *reinterpret_cast<const short*>(&h);
}

// ---------------- 1) AvgPool 8x8 -> xfT [B][N][C] bf16 (n-major) ----------------
__global__ void pool_kernel(const float* __restrict__ feat, short* __restrict__ xfT) {
    const int hp = blockIdx.x;   // 0..31
    const int cc = blockIdx.y;   // c-chunk of 8, 0..31
    const int b  = blockIdx.z;
    const int t  = threadIdx.x;
    const int ci = t >> 5, wp = t & 31;
    const int c = cc * 8 + ci;
    const float* base = feat + (((size_t)(b * C_ + c) * H_ + hp * 8) * W_) + wp * 8;
    float s = 0.f;
#pragma unroll
    for (int r = 0; r < 8; ++r) {
        const float4* p = reinterpret_cast<const float4*>(base + (size_t)r * W_);
        float4 a = p[0], d = p[1];
        s += a.x + a.y + a.z + a.w + d.x + d.y + d.z + d.w;
    }
    s *= (1.f / 64.f);
    __shared__ float lds[32][9];  // +1 pad: conflict-free transpose
    lds[wp][ci] = s;
    __syncthreads();
    if (t < 32) {
        short8 v;
#pragma unroll
        for (int j = 0; j < 8; ++j) v[j] = f2bf(lds[t][j]);
        *reinterpret_cast<short8*>(xfT + ((size_t)(b * N_ + hp * 32 + t) * C_) + cc * 8) = v;
    }
}

// ---------------- 2a) q,k projections -> qkT [B][N][64] bf16 (q:0..31, k:32..63) ----------------
__global__ void qk_kernel(const short* __restrict__ xfT,
                          const float* __restrict__ q_w, const float* __restrict__ q_b,
                          const float* __restrict__ k_w, const float* __restrict__ k_b,
                          short* __restrict__ qkT) {
    const int nblk = blockIdx.x, b = blockIdx.y;
    const int t = threadIdx.x, wv = t >> 6, l = t & 63;
    const int lr = l & 15, lg = l >> 4;
    const int nbase = nblk * 64 + wv * 16;
    floatx4 acc[4] = {};
    for (int ks = 0; ks < 8; ++ks) {
        const int cb = ks * 32 + lg * 8;
        short8 afrag = *reinterpret_cast<const short8*>(
            xfT + ((size_t)(b * N_ + nbase + lr) * C_) + cb);
#pragma unroll
        for (int ot = 0; ot < 4; ++ot) {
            const int o = ot * 16 + lr;
            const float* wrow = (o < 32) ? (q_w + (size_t)o * C_) : (k_w + (size_t)(o - 32) * C_);
            const float4* wp4 = reinterpret_cast<const float4*>(wrow + cb);
            float4 w0 = wp4[0], w1 = wp4[1];
            short8 bfrag;
            bfrag[0] = f2bf(w0.x); bfrag[1] = f2bf(w0.y); bfrag[2] = f2bf(w0.z); bfrag[3] = f2bf(w0.w);
            bfrag[4] = f2bf(w1.x); bfrag[5] = f2bf(w1.y); bfrag[6] = f2bf(w1.z); bfrag[7] = f2bf(w1.w);
            acc[ot] = __builtin_amdgcn_mfma_f32_16x16x32_bf16(afrag, bfrag, acc[ot], 0, 0, 0);
        }
    }
#pragma unroll
    for (int ot = 0; ot < 4; ++ot) {
        const int o = ot * 16 + lr;
        const float bias = (o < 32) ? q_b[o] : k_b[o - 32];
#pragma unroll
        for (int r = 0; r < 4; ++r) {
            const int n = nbase + lg * 4 + r;
            qkT[((size_t)(b * N_ + n)) * 64 + o] = f2bf(acc[ot][r] + bias);
        }
    }
}

// ---------------- 2b) v projection -> v [B][C][N] bf16 (m-major, PV's B layout) ----------------
__global__ void v_kernel(const short* __restrict__ xfT,
                         const float* __restrict__ v_w, const float* __restrict__ v_b,
                         short* __restrict__ vmat) {
    const int nblk = blockIdx.x, cblk = blockIdx.y, b = blockIdx.z;
    const int t = threadIdx.x, wv = t >> 6, l = t & 63;
    const int lr = l & 15, lg = l >> 4;
    const int cbase = cblk * 64 + wv * 16;
    const int nbase = nblk * 64;
    floatx4 acc[4] = {};
    for (int ks = 0; ks < 8; ++ks) {
        const int cin = ks * 32 + lg * 8;
        const float4* wp4 = reinterpret_cast<const float4*>(v_w + (size_t)(cbase + lr) * C_ + cin);
        float4 w0 = wp4[0], w1 = wp4[1];
        short8 afrag;
        afrag[0] = f2bf(w0.x); afrag[1] = f2bf(w0.y); afrag[2] = f2bf(w0.z); afrag[3] = f2bf(w0.w);
        afrag[4] = f2bf(w1.x); afrag[5] = f2bf(w1.y); afrag[6] = f2bf(w1.z); afrag[7] = f2bf(w1.w);
#pragma unroll
        for (int nt = 0; nt < 4; ++nt) {
            short8 bfrag = *reinterpret_cast<const short8*>(
                xfT + ((size_t)(b * N_ + nbase + nt * 16 + lr)) * C_ + cin);
            acc[nt] = __builtin_amdgcn_mfma_f32_16x16x32_bf16(afrag, bfrag, acc[nt], 0, 0, 0);
        }
    }
#pragma unroll
    for (int nt = 0; nt < 4; ++nt) {
#pragma unroll
        for (int r = 0; r < 4; ++r) {
            const int c = cbase + lg * 4 + r;
            const int n = nbase + nt * 16 + lr;
            vmat[((size_t)(b * C_ + c)) * N_ + n] = f2bf(acc[nt][r] + v_b[c]);
        }
    }
}

// ---------------- 3) energy + softmax -> att [B][N][N] bf16 ----------------
__global__ void attn_kernel(const short* __restrict__ qkT, short* __restrict__ att) {
    const int nblk = blockIdx.x, b = blockIdx.y;
    const int t = threadIdx.x, wv = t >> 6, l = t & 63;
    const int lr = l & 15, lg = l >> 4;
    const int nbase = nblk * 16;
    // A fragment: qT rows n, kk = key channel (contiguous in qkT)
    short8 afrag = *reinterpret_cast<const short8*>(
        qkT + ((size_t)(b * N_ + nbase + lr)) * 64 + lg * 8);
    floatx4 acc[16] = {};
#pragma unroll
    for (int mt = 0; mt < 16; ++mt) {
        const int m = wv * 256 + mt * 16 + lr;
        short8 bfrag = *reinterpret_cast<const short8*>(
            qkT + ((size_t)(b * N_ + m)) * 64 + 32 + lg * 8);
        acc[mt] = __builtin_amdgcn_mfma_f32_16x16x32_bf16(afrag, bfrag, acc[mt], 0, 0, 0);
    }
    const float scale = 0.17677669529663688f;  // 32^-0.5
#pragma unroll
    for (int mt = 0; mt < 16; ++mt) acc[mt] *= scale;

    __shared__ float smax[4][16];
    __shared__ float ssum[4][16];
    float mx[4], sm[4];
#pragma unroll
    for (int r = 0; r < 4; ++r) {
        float m = acc[0][r];
#pragma unroll
        for (int mt = 1; mt < 16; ++mt) m = fmaxf(m, acc[mt][r]);
        for (int off = 1; off < 16; off <<= 1) m = fmaxf(m, __shfl_xor(m, off, 64));
        mx[r] = m;
    }
    if (lr == 0) {
#pragma unroll
        for (int r = 0; r < 4; ++r) smax[wv][lg * 4 + r] = mx[r];
    }
    __syncthreads();
#pragma unroll
    for (int r = 0; r < 4; ++r) {
        float m = smax[0][lg * 4 + r];
        for (int w = 1; w < 4; ++w) m = fmaxf(m, smax[w][lg * 4 + r]);
        mx[r] = m;
        sm[r] = 0.f;
    }
#pragma unroll
    for (int mt = 0; mt < 16; ++mt) {
#pragma unroll
        for (int r = 0; r < 4; ++r) {
            float p = __expf(acc[mt][r] - mx[r]);
            acc[mt][r] = p;
            sm[r] += p;
        }
    }
#pragma unroll
    for (int r = 0; r < 4; ++r) {
        float s = sm[r];
        for (int off = 1; off < 16; off <<= 1) s += __shfl_xor(s, off, 64);
        sm[r] = s;
    }
    if (lr == 0) {
#pragma unroll
        for (int r = 0; r < 4; ++r) ssum[wv][lg * 4 + r] = sm[r];
    }
    __syncthreads();
    float inv[4];
#pragma unroll
    for (int r = 0; r < 4; ++r) {
        float s = 0.f;
        for (int w = 0; w < 4; ++w) s += ssum[w][lg * 4 + r];
        inv[r] = 1.f / s;
    }
#pragma unroll
    for (int mt = 0; mt < 16; ++mt) {
#pragma unroll
        for (int r = 0; r < 4; ++r) {
            att[((size_t)(b * N_ + nbase + lg * 4 + r)) * N_ + wv * 256 + mt * 16 + lr] =
                f2bf(acc[mt][r] * inv[r]);
        }
    }
}

// ---------------- 4) PV: out_sT[n][c] = sum_m att[n][m] * v[c][m] ----------------
__global__ void pv_kernel(const short* __restrict__ att, const short* __restrict__ vmat,
                          float* __restrict__ outsT) {
    const int nblk = blockIdx.x, b = blockIdx.y;  // n32 per block
    const int t = threadIdx.x, wv = t >> 6, l = t & 63;
    const int lr = l & 15, lg = l >> 4;
    const int nw = wv >> 1, cw = wv & 1;
    const int nbase = nblk * 32 + nw * 16;
    const int cbase = cw * 128;
    floatx4 acc[8] = {};
    for (int ks = 0; ks < 32; ++ks) {
        const int mb = ks * 32 + lg * 8;
        short8 afrag = *reinterpret_cast<const short8*>(
            att + ((size_t)(b * N_ + nbase + lr)) * N_ + mb);
#pragma unroll
        for (int ct = 0; ct < 8; ++ct) {
            short8 bfrag = *reinterpret_cast<const short8*>(
                vmat + ((size_t)(b * C_ + cbase + ct * 16 + lr)) * N_ + mb);
            acc[ct] = __builtin_amdgcn_mfma_f32_16x16x32_bf16(afrag, bfrag, acc[ct], 0, 0, 0);
        }
    }
#pragma unroll
    for (int ct = 0; ct < 8; ++ct) {
#pragma unroll
        for (int r = 0; r < 4; ++r) {
            outsT[((size_t)(b * N_ + nbase + lg * 4 + r)) * C_ + cbase + ct * 16 + lr] =
                acc[ct][r];
        }
    }
}

// ---------------- 5) upsample x8 (nearest) + residual ----------------
__global__ void final_kernel(const float* __restrict__ feat, const float* __restrict__ outsT,
                             float* __restrict__ out) {
    const int t = threadIdx.x;
    const size_t R = (size_t)blockIdx.x * 4 + (t >> 6);  // (b*256 + c)*256 + h
    const int wi = t & 63;
    const int b = (int)(R >> 16);
    const int c = (int)((R >> 8) & 255);
    const int h = (int)(R & 255);
    const int hp = h >> 3, wp = wi >> 1;  // wi*4 spans w in [wi*4, wi*4+3], all same w/8
    const size_t base = R * 256 + (size_t)wi * 4;
    float4 f = *reinterpret_cast<const float4*>(feat + base);
    const float s = outsT[((size_t)(b * N_ + hp * 32 + wp)) * C_ + c];
    f.x += s; f.y += s; f.z += s; f.w += s;
    *reinterpret_cast<float4*>(out + base) = f;
}

extern "C" void kernel_launch(void* const* d_in, const int* in_sizes, int n_in,
                              void* d_out, int out_size, void* d_ws, size_t ws_size,
                              hipStream_t stream) {
    const float* feat = (const float*)d_in[0];
    const float* q_w  = (const float*)d_in[1];
    const float* q_b  = (const float*)d_in[2];
    const float* k_w  = (const float*)d_in[3];
    const float* k_b  = (const float*)d_in[4];
    const float* v_w  = (const float*)d_in[5];
    const float* v_b  = (const float*)d_in[6];
    float* out = (float*)d_out;

    char* ws = (char*)d_ws;
    short* xfT   = (short*)(ws);                       // B*N*C*2   = 2 MB
    short* qkT   = (short*)(ws + 2097152);             // B*N*64*2  = 512 KB
    short* vmat  = (short*)(ws + 2621440);             // B*C*N*2   = 2 MB
    short* att   = (short*)(ws + 4718592);             // B*N*N*2   = 8 MB
    float* outsT = (float*)(ws + 13107200);            // B*N*C*4   = 4 MB

    pool_kernel <<<dim3(32, 32, B_), 256, 0, stream>>>(feat, xfT);
    qk_kernel   <<<dim3(16, B_),     256, 0, stream>>>(xfT, q_w, q_b, k_w, k_b, qkT);
    v_kernel    <<<dim3(16, 4, B_),  256, 0, stream>>>(xfT, v_w, v_b, vmat);
    attn_kernel <<<dim3(64, B_),     256, 0, stream>>>(qkT, att);
    pv_kernel   <<<dim3(32, B_),     256, 0, stream>>>(att, vmat, outsT);
    final_kernel<<<65536,            256, 0, stream>>>(feat, outsT, out);
}

// Round 3
// 538.432 us; speedup vs baseline: 1.0466x; 1.0466x over previous
//
#include <hip/hip_runtime.h>
#include <hip/hip_bf16.h>

#define B_ 4
#define C_ 256
#define H_ 256
#define W_ 256
#define N_ 1024   // 32*32 tokens
#define KC 32     // key channels

typedef __attribute__((ext_vector_type(8))) short short8;   // 8 bf16 (4 VGPRs)
typedef __attribute__((ext_vector_type(4))) float floatx4;  // MFMA C/D

__device__ __forceinline__ short f2bf(float x) {
    __hip_bfloat16 h = __float2bfloat16(x);
    return *reinterpret_cast<const short*>(&h);
}

// ---------------- 1) AvgPool 8x8 -> xfT [B][N][C] bf16 (n-major) ----------------
__global__ void pool_kernel(const float* __restrict__ feat, short* __restrict__ xfT) {
    const int hp = blockIdx.x;   // 0..31
    const int cc = blockIdx.y;   // c-chunk of 8, 0..31
    const int b  = blockIdx.z;
    const int t  = threadIdx.x;
    const int ci = t >> 5, wp = t & 31;
    const int c = cc * 8 + ci;
    const float* base = feat + (((size_t)(b * C_ + c) * H_ + hp * 8) * W_) + wp * 8;
    float s = 0.f;
#pragma unroll
    for (int r = 0; r < 8; ++r) {
        const float4* p = reinterpret_cast<const float4*>(base + (size_t)r * W_);
        float4 a = p[0], d = p[1];
        s += a.x + a.y + a.z + a.w + d.x + d.y + d.z + d.w;
    }
    s *= (1.f / 64.f);
    __shared__ float lds[32][9];  // +1 pad: conflict-free transpose
    lds[wp][ci] = s;
    __syncthreads();
    if (t < 32) {
        short8 v;
#pragma unroll
        for (int j = 0; j < 8; ++j) v[j] = f2bf(lds[t][j]);
        *reinterpret_cast<short8*>(xfT + ((size_t)(b * N_ + hp * 32 + t) * C_) + cc * 8) = v;
    }
}

// ---------------- 2) fused q,k,v projections ----------------
// blockIdx.x <  16 : qk path  -> qkT [B][N][64] bf16 (q:0..31, k:32..63)
// blockIdx.x >= 16 : v  path  -> vmat [B][C][N] bf16 (m-major, PV's B layout)
__global__ void qkv_kernel(const short* __restrict__ xfT,
                           const float* __restrict__ q_w, const float* __restrict__ q_b,
                           const float* __restrict__ k_w, const float* __restrict__ k_b,
                           const float* __restrict__ v_w, const float* __restrict__ v_b,
                           short* __restrict__ qkT, short* __restrict__ vmat) {
    const int b = blockIdx.y;
    const int t = threadIdx.x, wv = t >> 6, l = t & 63;
    const int lr = l & 15, lg = l >> 4;
    if (blockIdx.x < 16) {
        const int nblk = blockIdx.x;
        const int nbase = nblk * 64 + wv * 16;
        floatx4 acc[4] = {};
        for (int ks = 0; ks < 8; ++ks) {
            const int cb = ks * 32 + lg * 8;
            short8 afrag = *reinterpret_cast<const short8*>(
                xfT + ((size_t)(b * N_ + nbase + lr) * C_) + cb);
#pragma unroll
            for (int ot = 0; ot < 4; ++ot) {
                const int o = ot * 16 + lr;
                const float* wrow = (o < 32) ? (q_w + (size_t)o * C_) : (k_w + (size_t)(o - 32) * C_);
                const float4* wp4 = reinterpret_cast<const float4*>(wrow + cb);
                float4 w0 = wp4[0], w1 = wp4[1];
                short8 bfrag;
                bfrag[0] = f2bf(w0.x); bfrag[1] = f2bf(w0.y); bfrag[2] = f2bf(w0.z); bfrag[3] = f2bf(w0.w);
                bfrag[4] = f2bf(w1.x); bfrag[5] = f2bf(w1.y); bfrag[6] = f2bf(w1.z); bfrag[7] = f2bf(w1.w);
                acc[ot] = __builtin_amdgcn_mfma_f32_16x16x32_bf16(afrag, bfrag, acc[ot], 0, 0, 0);
            }
        }
#pragma unroll
        for (int ot = 0; ot < 4; ++ot) {
            const int o = ot * 16 + lr;
            const float bias = (o < 32) ? q_b[o] : k_b[o - 32];
#pragma unroll
            for (int r = 0; r < 4; ++r) {
                const int n = nbase + lg * 4 + r;
                qkT[((size_t)(b * N_ + n)) * 64 + o] = f2bf(acc[ot][r] + bias);
            }
        }
    } else {
        const int idx = blockIdx.x - 16;
        const int nblk = idx & 15, cblk = idx >> 4;
        const int cbase = cblk * 64 + wv * 16;
        const int nbase = nblk * 64;
        floatx4 acc[4] = {};
        for (int ks = 0; ks < 8; ++ks) {
            const int cin = ks * 32 + lg * 8;
            const float4* wp4 = reinterpret_cast<const float4*>(v_w + (size_t)(cbase + lr) * C_ + cin);
            float4 w0 = wp4[0], w1 = wp4[1];
            short8 afrag;
            afrag[0] = f2bf(w0.x); afrag[1] = f2bf(w0.y); afrag[2] = f2bf(w0.z); afrag[3] = f2bf(w0.w);
            afrag[4] = f2bf(w1.x); afrag[5] = f2bf(w1.y); afrag[6] = f2bf(w1.z); afrag[7] = f2bf(w1.w);
#pragma unroll
            for (int nt = 0; nt < 4; ++nt) {
                short8 bfrag = *reinterpret_cast<const short8*>(
                    xfT + ((size_t)(b * N_ + nbase + nt * 16 + lr)) * C_ + cin);
                acc[nt] = __builtin_amdgcn_mfma_f32_16x16x32_bf16(afrag, bfrag, acc[nt], 0, 0, 0);
            }
        }
#pragma unroll
        for (int nt = 0; nt < 4; ++nt) {
#pragma unroll
            for (int r = 0; r < 4; ++r) {
                const int c = cbase + lg * 4 + r;
                const int n = nbase + nt * 16 + lr;
                vmat[((size_t)(b * C_ + c)) * N_ + n] = f2bf(acc[nt][r] + v_b[c]);
            }
        }
    }
}

// ---------------- 3) energy + softmax -> att [B][N][N] bf16 ----------------
__global__ void attn_kernel(const short* __restrict__ qkT, short* __restrict__ att) {
    const int nblk = blockIdx.x, b = blockIdx.y;
    const int t = threadIdx.x, wv = t >> 6, l = t & 63;
    const int lr = l & 15, lg = l >> 4;
    const int nbase = nblk * 16;
    short8 afrag = *reinterpret_cast<const short8*>(
        qkT + ((size_t)(b * N_ + nbase + lr)) * 64 + lg * 8);
    floatx4 acc[16] = {};
#pragma unroll
    for (int mt = 0; mt < 16; ++mt) {
        const int m = wv * 256 + mt * 16 + lr;
        short8 bfrag = *reinterpret_cast<const short8*>(
            qkT + ((size_t)(b * N_ + m)) * 64 + 32 + lg * 8);
        acc[mt] = __builtin_amdgcn_mfma_f32_16x16x32_bf16(afrag, bfrag, acc[mt], 0, 0, 0);
    }
    const float scale = 0.17677669529663688f;  // 32^-0.5
#pragma unroll
    for (int mt = 0; mt < 16; ++mt) acc[mt] *= scale;

    __shared__ float smax[4][16];
    __shared__ float ssum[4][16];
    float mx[4], sm[4];
#pragma unroll
    for (int r = 0; r < 4; ++r) {
        float m = acc[0][r];
#pragma unroll
        for (int mt = 1; mt < 16; ++mt) m = fmaxf(m, acc[mt][r]);
        for (int off = 1; off < 16; off <<= 1) m = fmaxf(m, __shfl_xor(m, off, 64));
        mx[r] = m;
    }
    if (lr == 0) {
#pragma unroll
        for (int r = 0; r < 4; ++r) smax[wv][lg * 4 + r] = mx[r];
    }
    __syncthreads();
#pragma unroll
    for (int r = 0; r < 4; ++r) {
        float m = smax[0][lg * 4 + r];
        for (int w = 1; w < 4; ++w) m = fmaxf(m, smax[w][lg * 4 + r]);
        mx[r] = m;
        sm[r] = 0.f;
    }
#pragma unroll
    for (int mt = 0; mt < 16; ++mt) {
#pragma unroll
        for (int r = 0; r < 4; ++r) {
            float p = __expf(acc[mt][r] - mx[r]);
            acc[mt][r] = p;
            sm[r] += p;
        }
    }
#pragma unroll
    for (int r = 0; r < 4; ++r) {
        float s = sm[r];
        for (int off = 1; off < 16; off <<= 1) s += __shfl_xor(s, off, 64);
        sm[r] = s;
    }
    if (lr == 0) {
#pragma unroll
        for (int r = 0; r < 4; ++r) ssum[wv][lg * 4 + r] = sm[r];
    }
    __syncthreads();
    float inv[4];
#pragma unroll
    for (int r = 0; r < 4; ++r) {
        float s = 0.f;
        for (int w = 0; w < 4; ++w) s += ssum[w][lg * 4 + r];
        inv[r] = 1.f / s;
    }
#pragma unroll
    for (int mt = 0; mt < 16; ++mt) {
#pragma unroll
        for (int r = 0; r < 4; ++r) {
            att[((size_t)(b * N_ + nbase + lg * 4 + r)) * N_ + wv * 256 + mt * 16 + lr] =
                f2bf(acc[mt][r] * inv[r]);
        }
    }
}

// ---------------- 4) PV: out_sT[n][c] = sum_m att[n][m] * v[c][m] ----------------
// grid (64, B), 512 threads (8 waves). Wave: 16 n-rows x 32 c-cols, acc[2].
__global__ void pv_kernel(const short* __restrict__ att, const short* __restrict__ vmat,
                          float* __restrict__ outsT) {
    const int nblk = blockIdx.x, b = blockIdx.y;
    const int t = threadIdx.x, wv = t >> 6, l = t & 63;
    const int lr = l & 15, lg = l >> 4;
    const int nbase = nblk * 16;
    const int cbase = wv * 32;
    floatx4 acc[2] = {};
    const short* attrow = att + ((size_t)(b * N_ + nbase + lr)) * N_;
    const short* vrow0 = vmat + ((size_t)(b * C_ + cbase + lr)) * N_;
    const short* vrow1 = vmat + ((size_t)(b * C_ + cbase + 16 + lr)) * N_;
#pragma unroll 4
    for (int ks = 0; ks < 32; ++ks) {
        const int mb = ks * 32 + lg * 8;
        short8 afrag = *reinterpret_cast<const short8*>(attrow + mb);
        short8 b0 = *reinterpret_cast<const short8*>(vrow0 + mb);
        short8 b1 = *reinterpret_cast<const short8*>(vrow1 + mb);
        acc[0] = __builtin_amdgcn_mfma_f32_16x16x32_bf16(afrag, b0, acc[0], 0, 0, 0);
        acc[1] = __builtin_amdgcn_mfma_f32_16x16x32_bf16(afrag, b1, acc[1], 0, 0, 0);
    }
#pragma unroll
    for (int ct = 0; ct < 2; ++ct) {
#pragma unroll
        for (int r = 0; r < 4; ++r) {
            outsT[((size_t)(b * N_ + nbase + lg * 4 + r)) * C_ + cbase + ct * 16 + lr] =
                acc[ct][r];
        }
    }
}

// ---------------- 5) upsample x8 (nearest) + residual ----------------
__global__ void final_kernel(const float* __restrict__ feat, const float* __restrict__ outsT,
                             float* __restrict__ out) {
    const int t = threadIdx.x;
    const size_t R = (size_t)blockIdx.x * 4 + (t >> 6);  // (b*256 + c)*256 + h
    const int wi = t & 63;
    const int b = (int)(R >> 16);
    const int c = (int)((R >> 8) & 255);
    const int h = (int)(R & 255);
    const int hp = h >> 3, wp = wi >> 1;
    const size_t base = R * 256 + (size_t)wi * 4;
    float4 f = *reinterpret_cast<const float4*>(feat + base);
    const float s = outsT[((size_t)(b * N_ + hp * 32 + wp)) * C_ + c];
    f.x += s; f.y += s; f.z += s; f.w += s;
    *reinterpret_cast<float4*>(out + base) = f;
}

extern "C" void kernel_launch(void* const* d_in, const int* in_sizes, int n_in,
                              void* d_out, int out_size, void* d_ws, size_t ws_size,
                              hipStream_t stream) {
    const float* feat = (const float*)d_in[0];
    const float* q_w  = (const float*)d_in[1];
    const float* q_b  = (const float*)d_in[2];
    const float* k_w  = (const float*)d_in[3];
    const float* k_b  = (const float*)d_in[4];
    const float* v_w  = (const float*)d_in[5];
    const float* v_b  = (const float*)d_in[6];
    float* out = (float*)d_out;

    char* ws = (char*)d_ws;
    short* xfT   = (short*)(ws);                       // B*N*C*2   = 2 MB
    short* qkT   = (short*)(ws + 2097152);             // B*N*64*2  = 512 KB
    short* vmat  = (short*)(ws + 2621440);             // B*C*N*2   = 2 MB
    short* att   = (short*)(ws + 4718592);             // B*N*N*2   = 8 MB
    float* outsT = (float*)(ws + 13107200);            // B*N*C*4   = 4 MB

    pool_kernel <<<dim3(32, 32, B_), 256, 0, stream>>>(feat, xfT);
    qkv_kernel  <<<dim3(80, B_),     256, 0, stream>>>(xfT, q_w, q_b, k_w, k_b, v_w, v_b, qkT, vmat);
    attn_kernel <<<dim3(64, B_),     256, 0, stream>>>(qkT, att);
    pv_kernel   <<<dim3(64, B_),     512, 0, stream>>>(att, vmat, outsT);
    final_kernel<<<65536,            256, 0, stream>>>(feat, outsT, out);
}

// Round 4
// 529.641 us; speedup vs baseline: 1.0639x; 1.0166x over previous
//
#include <hip/hip_runtime.h>
#include <hip/hip_bf16.h>

#define B_ 4
#define C_ 256
#define H_ 256
#define W_ 256
#define N_ 1024   // 32*32 tokens
#define KC 32     // key channels

typedef __attribute__((ext_vector_type(8))) short short8;   // 8 bf16 (4 VGPRs)
typedef __attribute__((ext_vector_type(4))) float floatx4;  // MFMA C/D

__device__ __forceinline__ short f2bf(float x) {
    __hip_bfloat16 h = __float2bfloat16(x);
    return *reinterpret_cast<const short*>(&h);
}

// ---------------- 1) AvgPool 8x8 -> xfT [B][N][C] bf16 (n-major) ----------------
__global__ void pool_kernel(const float* __restrict__ feat, short* __restrict__ xfT) {
    const int hp = blockIdx.x;   // 0..31
    const int cc = blockIdx.y;   // c-chunk of 8, 0..31
    const int b  = blockIdx.z;
    const int t  = threadIdx.x;
    const int ci = t >> 5, wp = t & 31;
    const int c = cc * 8 + ci;
    const float* base = feat + (((size_t)(b * C_ + c) * H_ + hp * 8) * W_) + wp * 8;
    float s = 0.f;
#pragma unroll
    for (int r = 0; r < 8; ++r) {
        const float4* p = reinterpret_cast<const float4*>(base + (size_t)r * W_);
        float4 a = p[0], d = p[1];
        s += a.x + a.y + a.z + a.w + d.x + d.y + d.z + d.w;
    }
    s *= (1.f / 64.f);
    __shared__ float lds[32][9];  // +1 pad: conflict-free transpose
    lds[wp][ci] = s;
    __syncthreads();
    if (t < 32) {
        short8 v;
#pragma unroll
        for (int j = 0; j < 8; ++j) v[j] = f2bf(lds[t][j]);
        *reinterpret_cast<short8*>(xfT + ((size_t)(b * N_ + hp * 32 + t) * C_) + cc * 8) = v;
    }
}

// ---------------- 2) fused q,k,v projections ----------------
// blockIdx.x <  16 : qk path  -> qkT [B][N][64] bf16 (q:0..31, k:32..63)
// blockIdx.x >= 16 : v  path  -> vmat [B][C][N] bf16 (m-major, PV's B layout)
__global__ void qkv_kernel(const short* __restrict__ xfT,
                           const float* __restrict__ q_w, const float* __restrict__ q_b,
                           const float* __restrict__ k_w, const float* __restrict__ k_b,
                           const float* __restrict__ v_w, const float* __restrict__ v_b,
                           short* __restrict__ qkT, short* __restrict__ vmat) {
    const int b = blockIdx.y;
    const int t = threadIdx.x, wv = t >> 6, l = t & 63;
    const int lr = l & 15, lg = l >> 4;
    if (blockIdx.x < 16) {
        const int nblk = blockIdx.x;
        const int nbase = nblk * 64 + wv * 16;
        floatx4 acc[4] = {};
        for (int ks = 0; ks < 8; ++ks) {
            const int cb = ks * 32 + lg * 8;
            short8 afrag = *reinterpret_cast<const short8*>(
                xfT + ((size_t)(b * N_ + nbase + lr) * C_) + cb);
#pragma unroll
            for (int ot = 0; ot < 4; ++ot) {
                const int o = ot * 16 + lr;
                const float* wrow = (o < 32) ? (q_w + (size_t)o * C_) : (k_w + (size_t)(o - 32) * C_);
                const float4* wp4 = reinterpret_cast<const float4*>(wrow + cb);
                float4 w0 = wp4[0], w1 = wp4[1];
                short8 bfrag;
                bfrag[0] = f2bf(w0.x); bfrag[1] = f2bf(w0.y); bfrag[2] = f2bf(w0.z); bfrag[3] = f2bf(w0.w);
                bfrag[4] = f2bf(w1.x); bfrag[5] = f2bf(w1.y); bfrag[6] = f2bf(w1.z); bfrag[7] = f2bf(w1.w);
                acc[ot] = __builtin_amdgcn_mfma_f32_16x16x32_bf16(afrag, bfrag, acc[ot], 0, 0, 0);
            }
        }
#pragma unroll
        for (int ot = 0; ot < 4; ++ot) {
            const int o = ot * 16 + lr;
            const float bias = (o < 32) ? q_b[o] : k_b[o - 32];
#pragma unroll
            for (int r = 0; r < 4; ++r) {
                const int n = nbase + lg * 4 + r;
                qkT[((size_t)(b * N_ + n)) * 64 + o] = f2bf(acc[ot][r] + bias);
            }
        }
    } else {
        const int idx = blockIdx.x - 16;
        const int nblk = idx & 15, cblk = idx >> 4;
        const int cbase = cblk * 64 + wv * 16;
        const int nbase = nblk * 64;
        floatx4 acc[4] = {};
        for (int ks = 0; ks < 8; ++ks) {
            const int cin = ks * 32 + lg * 8;
            const float4* wp4 = reinterpret_cast<const float4*>(v_w + (size_t)(cbase + lr) * C_ + cin);
            float4 w0 = wp4[0], w1 = wp4[1];
            short8 afrag;
            afrag[0] = f2bf(w0.x); afrag[1] = f2bf(w0.y); afrag[2] = f2bf(w0.z); afrag[3] = f2bf(w0.w);
            afrag[4] = f2bf(w1.x); afrag[5] = f2bf(w1.y); afrag[6] = f2bf(w1.z); afrag[7] = f2bf(w1.w);
#pragma unroll
            for (int nt = 0; nt < 4; ++nt) {
                short8 bfrag = *reinterpret_cast<const short8*>(
                    xfT + ((size_t)(b * N_ + nbase + nt * 16 + lr)) * C_ + cin);
                acc[nt] = __builtin_amdgcn_mfma_f32_16x16x32_bf16(afrag, bfrag, acc[nt], 0, 0, 0);
            }
        }
#pragma unroll
        for (int nt = 0; nt < 4; ++nt) {
#pragma unroll
            for (int r = 0; r < 4; ++r) {
                const int c = cbase + lg * 4 + r;
                const int n = nbase + nt * 16 + lr;
                vmat[((size_t)(b * C_ + c)) * N_ + n] = f2bf(acc[nt][r] + v_b[c]);
            }
        }
    }
}

// ---------------- 3) fused energy + softmax + PV ----------------
// grid (64, B), 512 threads (8 waves). Block: 16 q-rows.
// Phase A: each wave computes energy for m-chunk of 128 (8 MFMAs).
// Phase B: softmax (in-register + cross-wave LDS reduce), P -> LDS bf16 (swizzled).
// Phase C: PV. Each wave: c-chunk of 32, A-frags from LDS, B-frags (vmat) from L2.
__global__ void attnpv_kernel(const short* __restrict__ qkT, const short* __restrict__ vmat,
                              float* __restrict__ outsT) {
    const int nblk = blockIdx.x, b = blockIdx.y;
    const int t = threadIdx.x, wv = t >> 6, l = t & 63;
    const int lr = l & 15, lg = l >> 4;
    const int nbase = nblk * 16;

    __shared__ short plds[16 * 1024];   // P tile [16 q-rows][1024 m], XOR-swizzled
    __shared__ float smax[8][16];
    __shared__ float ssum[8][16];

    // --- Phase A: energy ---
    short8 afrag = *reinterpret_cast<const short8*>(
        qkT + ((size_t)(b * N_ + nbase + lr)) * 64 + lg * 8);
    floatx4 acc[8] = {};
#pragma unroll
    for (int mt = 0; mt < 8; ++mt) {
        const int m = wv * 128 + mt * 16 + lr;
        short8 bfrag = *reinterpret_cast<const short8*>(
            qkT + ((size_t)(b * N_ + m)) * 64 + 32 + lg * 8);
        acc[mt] = __builtin_amdgcn_mfma_f32_16x16x32_bf16(afrag, bfrag, acc[mt], 0, 0, 0);
    }
    const float scale = 0.17677669529663688f;  // 32^-0.5
#pragma unroll
    for (int mt = 0; mt < 8; ++mt) acc[mt] *= scale;

    // --- Phase B: softmax ---
    float mx[4], sm[4];
#pragma unroll
    for (int r = 0; r < 4; ++r) {
        float m = acc[0][r];
#pragma unroll
        for (int mt = 1; mt < 8; ++mt) m = fmaxf(m, acc[mt][r]);
        for (int off = 1; off < 16; off <<= 1) m = fmaxf(m, __shfl_xor(m, off, 64));
        mx[r] = m;
    }
    if (lr == 0) {
#pragma unroll
        for (int r = 0; r < 4; ++r) smax[wv][lg * 4 + r] = mx[r];
    }
    __syncthreads();
#pragma unroll
    for (int r = 0; r < 4; ++r) {
        float m = smax[0][lg * 4 + r];
#pragma unroll
        for (int w = 1; w < 8; ++w) m = fmaxf(m, smax[w][lg * 4 + r]);
        mx[r] = m;
        sm[r] = 0.f;
    }
#pragma unroll
    for (int mt = 0; mt < 8; ++mt) {
#pragma unroll
        for (int r = 0; r < 4; ++r) {
            float p = __expf(acc[mt][r] - mx[r]);
            acc[mt][r] = p;
            sm[r] += p;
        }
    }
#pragma unroll
    for (int r = 0; r < 4; ++r) {
        float s = sm[r];
        for (int off = 1; off < 16; off <<= 1) s += __shfl_xor(s, off, 64);
        sm[r] = s;
    }
    if (lr == 0) {
#pragma unroll
        for (int r = 0; r < 4; ++r) ssum[wv][lg * 4 + r] = sm[r];
    }
    __syncthreads();
    float inv[4];
#pragma unroll
    for (int r = 0; r < 4; ++r) {
        float s = 0.f;
#pragma unroll
        for (int w = 0; w < 8; ++w) s += ssum[w][lg * 4 + r];
        inv[r] = 1.f / s;
    }
    // P -> LDS (bf16), swizzled: short-index ^= (row&7)<<3 (16B granularity)
#pragma unroll
    for (int mt = 0; mt < 8; ++mt) {
#pragma unroll
        for (int r = 0; r < 4; ++r) {
            const int row = lg * 4 + r;
            const int col = wv * 128 + mt * 16 + lr;
            plds[(row * 1024 + col) ^ ((row & 7) << 3)] = f2bf(acc[mt][r] * inv[r]);
        }
    }
    __syncthreads();

    // --- Phase C: PV ---
    const int cbase = wv * 32;
    floatx4 oacc[2] = {};
    const short* vrow0 = vmat + ((size_t)(b * C_ + cbase + lr)) * N_;
    const short* vrow1 = vmat + ((size_t)(b * C_ + cbase + 16 + lr)) * N_;
#pragma unroll 4
    for (int ks = 0; ks < 32; ++ks) {
        const int mb = ks * 32 + lg * 8;
        short8 pa = *reinterpret_cast<const short8*>(
            &plds[(lr * 1024 + mb) ^ ((lr & 7) << 3)]);
        short8 b0 = *reinterpret_cast<const short8*>(vrow0 + mb);
        short8 b1 = *reinterpret_cast<const short8*>(vrow1 + mb);
        oacc[0] = __builtin_amdgcn_mfma_f32_16x16x32_bf16(pa, b0, oacc[0], 0, 0, 0);
        oacc[1] = __builtin_amdgcn_mfma_f32_16x16x32_bf16(pa, b1, oacc[1], 0, 0, 0);
    }
#pragma unroll
    for (int ct = 0; ct < 2; ++ct) {
#pragma unroll
        for (int r = 0; r < 4; ++r) {
            outsT[((size_t)(b * N_ + nbase + lg * 4 + r)) * C_ + cbase + ct * 16 + lr] =
                oacc[ct][r];
        }
    }
}

// ---------------- 4) upsample x8 (nearest) + residual ----------------
__global__ void final_kernel(const float* __restrict__ feat, const float* __restrict__ outsT,
                             float* __restrict__ out) {
    const int t = threadIdx.x;
    const size_t R = (size_t)blockIdx.x * 4 + (t >> 6);  // (b*256 + c)*256 + h
    const int wi = t & 63;
    const int b = (int)(R >> 16);
    const int c = (int)((R >> 8) & 255);
    const int h = (int)(R & 255);
    const int hp = h >> 3, wp = wi >> 1;
    const size_t base = R * 256 + (size_t)wi * 4;
    float4 f = *reinterpret_cast<const float4*>(feat + base);
    const float s = outsT[((size_t)(b * N_ + hp * 32 + wp)) * C_ + c];
    f.x += s; f.y += s; f.z += s; f.w += s;
    *reinterpret_cast<float4*>(out + base) = f;
}

extern "C" void kernel_launch(void* const* d_in, const int* in_sizes, int n_in,
                              void* d_out, int out_size, void* d_ws, size_t ws_size,
                              hipStream_t stream) {
    const float* feat = (const float*)d_in[0];
    const float* q_w  = (const float*)d_in[1];
    const float* q_b  = (const float*)d_in[2];
    const float* k_w  = (const float*)d_in[3];
    const float* k_b  = (const float*)d_in[4];
    const float* v_w  = (const float*)d_in[5];
    const float* v_b  = (const float*)d_in[6];
    float* out = (float*)d_out;

    char* ws = (char*)d_ws;
    short* xfT   = (short*)(ws);                       // B*N*C*2   = 2 MB
    short* qkT   = (short*)(ws + 2097152);             // B*N*64*2  = 512 KB
    short* vmat  = (short*)(ws + 2621440);             // B*C*N*2   = 2 MB
    float* outsT = (float*)(ws + 4718592);             // B*N*C*4   = 4 MB

    pool_kernel  <<<dim3(32, 32, B_), 256, 0, stream>>>(feat, xfT);
    qkv_kernel   <<<dim3(80, B_),     256, 0, stream>>>(xfT, q_w, q_b, k_w, k_b, v_w, v_b, qkT, vmat);
    attnpv_kernel<<<dim3(64, B_),     512, 0, stream>>>(qkT, vmat, outsT);
    final_kernel <<<65536,            256, 0, stream>>>(feat, outsT, out);
}